// Round 3
// baseline (1439.344 us; speedup 1.0000x reference)
//
#include <hip/hip_runtime.h>
#include <hip/hip_bf16.h>

typedef float v4f __attribute__((ext_vector_type(4)));

#define H 64
#define EPS 1e-5f
#define BLOCK 128

// One thread per edge. No per-thread arrays anywhere (scratch-proof):
//  - GEMM1 streams h granules to LDS (unnormalized) with online LN1 stats.
//  - GEMM2 reads h back (XOR-swizzled, ~conflict-free), applies LN1+ReLU on
//    the fly, accumulates into 16 *named* v4f registers.
//  - All weight/bias addresses are wave-uniform -> s_load; v_fmac reads SGPR.
//  - No __syncthreads: each thread touches only its own LDS row.
__global__ void __launch_bounds__(BLOCK, 2) edge_mlp_kernel(
    const float* __restrict__ pos,   // (N,3)
    const float* __restrict__ vel,   // (N,3)
    const int*   __restrict__ eidx,  // (2,E) int32
    const float* __restrict__ W1,    // (8,H)
    const float* __restrict__ b1,
    const float* __restrict__ g1,
    const float* __restrict__ be1,
    const float* __restrict__ W2,    // (H,H)
    const float* __restrict__ b2,
    const float* __restrict__ g2,
    const float* __restrict__ be2,
    float* __restrict__ out,         // (E,H)
    int E)
{
    __shared__ v4f hbuf[BLOCK * 16];   // 32 KB: per-thread 16 granules of h

    const int tid = threadIdx.x;
    const int e = blockIdx.x * BLOCK + tid;
    if (e >= E) return;                // safe: no barriers in this kernel

    const int s = eidx[e];
    const int t = eidx[E + e];

    const float f0 = pos[3*t+0] - pos[3*s+0];
    const float f1 = pos[3*t+1] - pos[3*s+1];
    const float f2 = pos[3*t+2] - pos[3*s+2];
    const float f3 = sqrtf(f0*f0 + f1*f1 + f2*f2);
    const float f4 = vel[3*t+0] - vel[3*s+0];
    const float f5 = vel[3*t+1] - vel[3*s+1];
    const float f6 = vel[3*t+2] - vel[3*s+2];
    const float f7 = sqrtf(f4*f4 + f5*f5 + f6*f6);

    const int base = tid * 16;
    const int sw   = tid & 15;

    // ---- GEMM1: feats @ W1 + b1, online stats, stream granules to LDS ----
    float m1 = 0.f, q1 = 0.f;
#pragma unroll
    for (int q = 0; q < 16; ++q) {
        v4f a = *(const v4f*)(b1 + 4*q);
        a += f0 * *(const v4f*)(W1 + 0*H + 4*q);
        a += f1 * *(const v4f*)(W1 + 1*H + 4*q);
        a += f2 * *(const v4f*)(W1 + 2*H + 4*q);
        a += f3 * *(const v4f*)(W1 + 3*H + 4*q);
        a += f4 * *(const v4f*)(W1 + 4*H + 4*q);
        a += f5 * *(const v4f*)(W1 + 5*H + 4*q);
        a += f6 * *(const v4f*)(W1 + 6*H + 4*q);
        a += f7 * *(const v4f*)(W1 + 7*H + 4*q);
        m1 += a[0] + a[1] + a[2] + a[3];
        q1 = fmaf(a[0], a[0], q1);
        q1 = fmaf(a[1], a[1], q1);
        q1 = fmaf(a[2], a[2], q1);
        q1 = fmaf(a[3], a[3], q1);
        hbuf[base + (q ^ sw)] = a;
    }
    const float mu1  = m1 * (1.0f / H);
    const float var1 = fmaf(-mu1, mu1, q1 * (1.0f / H));
    const float rs1  = rsqrtf(var1 + EPS);
    const float c1   = -mu1 * rs1;

    // ---- GEMM2 accumulators: 16 named v4f (64 VGPRs, no arrays) ----
    v4f A0  = *(const v4f*)(b2 +  0);
    v4f A1  = *(const v4f*)(b2 +  4);
    v4f A2  = *(const v4f*)(b2 +  8);
    v4f A3  = *(const v4f*)(b2 + 12);
    v4f A4  = *(const v4f*)(b2 + 16);
    v4f A5  = *(const v4f*)(b2 + 20);
    v4f A6  = *(const v4f*)(b2 + 24);
    v4f A7  = *(const v4f*)(b2 + 28);
    v4f A8  = *(const v4f*)(b2 + 32);
    v4f A9  = *(const v4f*)(b2 + 36);
    v4f A10 = *(const v4f*)(b2 + 40);
    v4f A11 = *(const v4f*)(b2 + 44);
    v4f A12 = *(const v4f*)(b2 + 48);
    v4f A13 = *(const v4f*)(b2 + 52);
    v4f A14 = *(const v4f*)(b2 + 56);
    v4f A15 = *(const v4f*)(b2 + 60);

#define GEMM2_ROW(hn, krow) do {                                   \
        const float* Wr_ = W2 + (krow) * H;                        \
        A0  += (hn) * *(const v4f*)(Wr_ +  0);                     \
        A1  += (hn) * *(const v4f*)(Wr_ +  4);                     \
        A2  += (hn) * *(const v4f*)(Wr_ +  8);                     \
        A3  += (hn) * *(const v4f*)(Wr_ + 12);                     \
        A4  += (hn) * *(const v4f*)(Wr_ + 16);                     \
        A5  += (hn) * *(const v4f*)(Wr_ + 20);                     \
        A6  += (hn) * *(const v4f*)(Wr_ + 24);                     \
        A7  += (hn) * *(const v4f*)(Wr_ + 28);                     \
        A8  += (hn) * *(const v4f*)(Wr_ + 32);                     \
        A9  += (hn) * *(const v4f*)(Wr_ + 36);                     \
        A10 += (hn) * *(const v4f*)(Wr_ + 40);                     \
        A11 += (hn) * *(const v4f*)(Wr_ + 44);                     \
        A12 += (hn) * *(const v4f*)(Wr_ + 48);                     \
        A13 += (hn) * *(const v4f*)(Wr_ + 52);                     \
        A14 += (hn) * *(const v4f*)(Wr_ + 56);                     \
        A15 += (hn) * *(const v4f*)(Wr_ + 60);                     \
    } while (0)

#pragma unroll
    for (int kk = 0; kk < 16; ++kk) {
        const v4f hv = hbuf[base + (kk ^ sw)];
        const v4f gk = *(const v4f*)(g1  + 4*kk);
        const v4f bk = *(const v4f*)(be1 + 4*kk);
        const float hn0 = fmaxf(fmaf(fmaf(hv[0], rs1, c1), gk[0], bk[0]), 0.f);
        const float hn1 = fmaxf(fmaf(fmaf(hv[1], rs1, c1), gk[1], bk[1]), 0.f);
        const float hn2 = fmaxf(fmaf(fmaf(hv[2], rs1, c1), gk[2], bk[2]), 0.f);
        const float hn3 = fmaxf(fmaf(fmaf(hv[3], rs1, c1), gk[3], bk[3]), 0.f);
        GEMM2_ROW(hn0, 4*kk + 0);
        GEMM2_ROW(hn1, 4*kk + 1);
        GEMM2_ROW(hn2, 4*kk + 2);
        GEMM2_ROW(hn3, 4*kk + 3);
    }
#undef GEMM2_ROW

    // ---- LN2 stats over the 16 named accumulators ----
    v4f sv = A0;
    sv += A1;  sv += A2;  sv += A3;  sv += A4;  sv += A5;
    sv += A6;  sv += A7;  sv += A8;  sv += A9;  sv += A10;
    sv += A11; sv += A12; sv += A13; sv += A14; sv += A15;
    const float m2s = sv[0] + sv[1] + sv[2] + sv[3];

    v4f qv = A0 * A0;
    qv += A1*A1;   qv += A2*A2;   qv += A3*A3;   qv += A4*A4;
    qv += A5*A5;   qv += A6*A6;   qv += A7*A7;   qv += A8*A8;
    qv += A9*A9;   qv += A10*A10; qv += A11*A11; qv += A12*A12;
    qv += A13*A13; qv += A14*A14; qv += A15*A15;
    const float q2s = qv[0] + qv[1] + qv[2] + qv[3];

    const float mu2  = m2s * (1.0f / H);
    const float var2 = fmaf(-mu2, mu2, q2s * (1.0f / H));
    const float rs2  = rsqrtf(var2 + EPS);
    const float c2   = -mu2 * rs2;

    float* o = out + (size_t)e * H;

#define STORE_Q(q, Aq) do {                                              \
        const v4f gq = *(const v4f*)(g2  + 4*(q));                       \
        const v4f bq = *(const v4f*)(be2 + 4*(q));                       \
        v4f y;                                                           \
        y[0] = fmaxf(fmaf(fmaf(Aq[0], rs2, c2), gq[0], bq[0]), 0.f);     \
        y[1] = fmaxf(fmaf(fmaf(Aq[1], rs2, c2), gq[1], bq[1]), 0.f);     \
        y[2] = fmaxf(fmaf(fmaf(Aq[2], rs2, c2), gq[2], bq[2]), 0.f);     \
        y[3] = fmaxf(fmaf(fmaf(Aq[3], rs2, c2), gq[3], bq[3]), 0.f);     \
        *(v4f*)(o + 4*(q)) = y;                                          \
    } while (0)

    STORE_Q(0,  A0);  STORE_Q(1,  A1);  STORE_Q(2,  A2);  STORE_Q(3,  A3);
    STORE_Q(4,  A4);  STORE_Q(5,  A5);  STORE_Q(6,  A6);  STORE_Q(7,  A7);
    STORE_Q(8,  A8);  STORE_Q(9,  A9);  STORE_Q(10, A10); STORE_Q(11, A11);
    STORE_Q(12, A12); STORE_Q(13, A13); STORE_Q(14, A14); STORE_Q(15, A15);
#undef STORE_Q
}

extern "C" void kernel_launch(void* const* d_in, const int* in_sizes, int n_in,
                              void* d_out, int out_size, void* d_ws, size_t ws_size,
                              hipStream_t stream) {
    const float* pos = (const float*)d_in[0];
    const float* vel = (const float*)d_in[1];
    const int*  eidx = (const int*)d_in[2];
    const float* W1  = (const float*)d_in[3];
    const float* b1  = (const float*)d_in[4];
    const float* g1  = (const float*)d_in[5];
    const float* be1 = (const float*)d_in[6];
    const float* W2  = (const float*)d_in[7];
    const float* b2  = (const float*)d_in[8];
    const float* g2  = (const float*)d_in[9];
    const float* be2 = (const float*)d_in[10];
    float* out = (float*)d_out;

    const int E = in_sizes[2] / 2;
    const int grid = (E + BLOCK - 1) / BLOCK;
    edge_mlp_kernel<<<grid, BLOCK, 0, stream>>>(pos, vel, eidx, W1, b1, g1, be1,
                                                W2, b2, g2, be2, out, E);
}

// Round 7
// 1123.849 us; speedup vs baseline: 1.2807x; 1.2807x over previous
//
#include <hip/hip_runtime.h>

typedef float v4f __attribute__((ext_vector_type(4)));
typedef short bf8 __attribute__((ext_vector_type(8)));   // 8 bf16 (bit patterns in shorts)

#define H 64
#define EPS 1e-5f
#define GPB 8        // 64-edge macro-tiles per block

__device__ __forceinline__ unsigned short f2bf(float x) {
    unsigned u = __float_as_uint(x);
    unsigned r = (u + 0x7FFFu + ((u >> 16) & 1u)) >> 16;   // RNE
    return (unsigned short)r;
}
__device__ __forceinline__ float bf2f(unsigned short h) {
    return __uint_as_float(((unsigned)h) << 16);
}

#define MFMA16(a, b, c) __builtin_amdgcn_mfma_f32_16x16x32_bf16((a), (b), (c), 0, 0, 0)

// One wave (64 threads) per block. Per macro-tile of 64 edges:
//   Phase A (lane = edge): gather, GEMM1 fp32, online LN1 stats, raw h -> LDS (swizzled).
//   Phase B (4 M-tiles of 16 edges): LDS->A-frags with LN1+ReLU+affine applied on the fly,
//   bf16x3 split, 24 MFMA per tile vs register-resident W2 fragments, LN2 via shfl_xor,
//   coalesced stores. W2 is loaded ONCE per block (bf16 hi/lo fragments, 64 VGPRs) —
//   this removes the per-wave 16KB W2 s_load stream that flat-lined rounds 1-3.
__global__ void __launch_bounds__(64, 2) edge_mlp_mfma(
    const float* __restrict__ pos,   // (N,3)
    const float* __restrict__ vel,   // (N,3)
    const int*   __restrict__ eidx,  // (2,E)
    const float* __restrict__ W1,    // (8,H)
    const float* __restrict__ b1,
    const float* __restrict__ g1,
    const float* __restrict__ be1,
    const float* __restrict__ W2,    // (H,H) row-major [k][n]
    const float* __restrict__ b2,
    const float* __restrict__ g2,
    const float* __restrict__ be2,
    float* __restrict__ out,         // (E,H)
    int E)
{
    __shared__ v4f    hbuf[64 * 16];   // 16 KB raw h (fp32), chunk-swizzled
    __shared__ float2 scbuf[64];       // per-edge (rs1, c1)

    const int L   = threadIdx.x;   // lane 0..63
    const int g16 = L >> 4;        // k-group 0..3
    const int l16 = L & 15;        // row/col within 16-tile

    // ---------- per-block preloads ----------
    // W2 B-fragments, bf16 hi/lo, slot->k map: k = c*32 + g16*8 + j  (same map used for A)
    bf8 BH00, BL00, BH01, BL01, BH10, BL10, BH11, BL11,
        BH20, BL20, BH21, BL21, BH30, BL30, BH31, BL31;
#define LOAD_B(n, c, BH, BL) do {                                        \
        const int col_ = (n)*16 + l16;                                   \
        _Pragma("unroll")                                                \
        for (int j = 0; j < 8; ++j) {                                    \
            float w_ = W2[((c)*32 + g16*8 + j) * H + col_];              \
            unsigned short hi_ = f2bf(w_);                               \
            BH[j] = (short)hi_;                                          \
            BL[j] = (short)f2bf(w_ - bf2f(hi_));                         \
        }                                                                \
    } while (0)
    LOAD_B(0, 0, BH00, BL00); LOAD_B(0, 1, BH01, BL01);
    LOAD_B(1, 0, BH10, BL10); LOAD_B(1, 1, BH11, BL11);
    LOAD_B(2, 0, BH20, BL20); LOAD_B(2, 1, BH21, BL21);
    LOAD_B(3, 0, BH30, BL30); LOAD_B(3, 1, BH31, BL31);
#undef LOAD_B

    // LN1 gamma/beta for this lane's k-slots (c=0/1, elements j0-3 / j4-7)
    v4f G10a, G10b, G11a, G11b, BE10a, BE10b, BE11a, BE11b;
#pragma unroll
    for (int j = 0; j < 4; ++j) {
        G10a[j]  = g1 [ 0 + g16*8 + j];
        G10b[j]  = g1 [ 0 + g16*8 + 4 + j];
        G11a[j]  = g1 [32 + g16*8 + j];
        G11b[j]  = g1 [32 + g16*8 + 4 + j];
        BE10a[j] = be1[ 0 + g16*8 + j];
        BE10b[j] = be1[ 0 + g16*8 + 4 + j];
        BE11a[j] = be1[32 + g16*8 + j];
        BE11b[j] = be1[32 + g16*8 + 4 + j];
    }
    // LN2 / bias fragments: element n -> column n*16 + l16
    v4f B2f, G2f, BE2f;
#pragma unroll
    for (int n = 0; n < 4; ++n) {
        B2f[n]  = b2 [n*16 + l16];
        G2f[n]  = g2 [n*16 + l16];
        BE2f[n] = be2[n*16 + l16];
    }

    // Build A-fragment (one c-half): LN1+affine+ReLU on the fly, bf16 hi/lo split.
#define BUILD_A(c, Ga, Gb, Ba, Bb, AH, AL) do {                          \
        const int q0_ = (c)*8 + g16*2;                                   \
        v4f x0_ = hbuf[erow*16 + ((q0_)     ^ (erow & 7))];              \
        v4f x1_ = hbuf[erow*16 + ((q0_ + 1) ^ (erow & 7))];              \
        _Pragma("unroll")                                                \
        for (int j = 0; j < 4; ++j) {                                    \
            float y_ = fmaf(x0_[j], scv.x, scv.y);                       \
            y_ = fmaxf(fmaf(y_, Ga[j], Ba[j]), 0.f);                     \
            unsigned short h_ = f2bf(y_);                                \
            AH[j] = (short)h_;                                           \
            AL[j] = (short)f2bf(y_ - bf2f(h_));                         \
            float z_ = fmaf(x1_[j], scv.x, scv.y);                       \
            z_ = fmaxf(fmaf(z_, Gb[j], Bb[j]), 0.f);                     \
            unsigned short h2_ = f2bf(z_);                               \
            AH[j + 4] = (short)h2_;                                      \
            AL[j + 4] = (short)f2bf(z_ - bf2f(h2_));                     \
        }                                                                \
    } while (0)

    // bf16x3: Ah*Bh + Ah*Bl + Al*Bh over both K-halves
#define ACC_N(acc, BHc0, BLc0, BHc1, BLc1) do {                          \
        acc = MFMA16(AH0, BHc0, acc);                                    \
        acc = MFMA16(AH0, BLc0, acc);                                    \
        acc = MFMA16(AL0, BHc0, acc);                                    \
        acc = MFMA16(AH1, BHc1, acc);                                    \
        acc = MFMA16(AH1, BLc1, acc);                                    \
        acc = MFMA16(AL1, BHc1, acc);                                    \
    } while (0)

#define STORE_N(n, acn) do {                                             \
        _Pragma("unroll")                                                \
        for (int r = 0; r < 4; ++r) {                                    \
            float y_ = fmaf(fmaf(acn[r], RS2[r], C2[r]), G2f[n], BE2f[n]); \
            y_ = fmaxf(y_, 0.f);                                         \
            if (full || (ebase + r) < E)                                 \
                out[(size_t)(ebase + r) * H + (n)*16 + l16] = y_;        \
        }                                                                \
    } while (0)

#define M_TILE(m) do {                                                   \
        const int erow = (m)*16 + l16;                                   \
        const float2 scv = scbuf[erow];                                  \
        bf8 AH0, AL0, AH1, AL1;                                          \
        BUILD_A(0, G10a, G10b, BE10a, BE10b, AH0, AL0);                  \
        BUILD_A(1, G11a, G11b, BE11a, BE11b, AH1, AL1);                  \
        v4f ac0 = {0.f, 0.f, 0.f, 0.f};                                  \
        v4f ac1 = ac0, ac2 = ac0, ac3 = ac0;                             \
        ACC_N(ac0, BH00, BL00, BH01, BL01);                              \
        ACC_N(ac1, BH10, BL10, BH11, BL11);                              \
        ACC_N(ac2, BH20, BL20, BH21, BL21);                              \
        ACC_N(ac3, BH30, BL30, BH31, BL31);                              \
        ac0 += B2f[0]; ac1 += B2f[1]; ac2 += B2f[2]; ac3 += B2f[3];      \
        v4f sv = ac0 + ac1 + ac2 + ac3;                                  \
        v4f qv = ac0*ac0 + ac1*ac1 + ac2*ac2 + ac3*ac3;                  \
        _Pragma("unroll")                                                \
        for (int msk = 1; msk < 16; msk <<= 1) {                         \
            sv[0] += __shfl_xor(sv[0], msk);                             \
            sv[1] += __shfl_xor(sv[1], msk);                             \
            sv[2] += __shfl_xor(sv[2], msk);                             \
            sv[3] += __shfl_xor(sv[3], msk);                             \
            qv[0] += __shfl_xor(qv[0], msk);                             \
            qv[1] += __shfl_xor(qv[1], msk);                             \
            qv[2] += __shfl_xor(qv[2], msk);                             \
            qv[3] += __shfl_xor(qv[3], msk);                             \
        }                                                                \
        v4f RS2, C2;                                                     \
        _Pragma("unroll")                                                \
        for (int r = 0; r < 4; ++r) {                                    \
            float mu_  = sv[r] * (1.0f / H);                             \
            float var_ = fmaf(-mu_, mu_, qv[r] * (1.0f / H));            \
            float rs_  = rsqrtf(var_ + EPS);                             \
            RS2[r] = rs_;                                                \
            C2[r]  = -mu_ * rs_;                                         \
        }                                                                \
        const int ebase = mb + (m)*16 + g16*4;                           \
        STORE_N(0, ac0); STORE_N(1, ac1);                                \
        STORE_N(2, ac2); STORE_N(3, ac3);                                \
    } while (0)

    // ---------- main loop over macro-tiles ----------
    int mb = blockIdx.x * (64 * GPB);
    for (int it = 0; it < GPB; ++it, mb += 64) {
        if (mb >= E) break;                      // wave-uniform
        const bool full = (mb + 64 <= E);

        // ---- Phase A: per-lane edge ----
        int e = mb + L;
        if (e >= E) e = E - 1;                   // clamp (stores are guarded)
        const int s = eidx[e];
        const int t = eidx[E + e];
        const float f0 = pos[3*t+0] - pos[3*s+0];
        const float f1 = pos[3*t+1] - pos[3*s+1];
        const float f2 = pos[3*t+2] - pos[3*s+2];
        const float f3 = sqrtf(f0*f0 + f1*f1 + f2*f2);
        const float f4 = vel[3*t+0] - vel[3*s+0];
        const float f5 = vel[3*t+1] - vel[3*s+1];
        const float f6 = vel[3*t+2] - vel[3*s+2];
        const float f7 = sqrtf(f4*f4 + f5*f5 + f6*f6);

        float m1 = 0.f, q1 = 0.f;
#pragma unroll
        for (int q = 0; q < 16; ++q) {
            v4f a = *(const v4f*)(b1 + 4*q);
            a += f0 * *(const v4f*)(W1 + 0*H + 4*q);
            a += f1 * *(const v4f*)(W1 + 1*H + 4*q);
            a += f2 * *(const v4f*)(W1 + 2*H + 4*q);
            a += f3 * *(const v4f*)(W1 + 3*H + 4*q);
            a += f4 * *(const v4f*)(W1 + 4*H + 4*q);
            a += f5 * *(const v4f*)(W1 + 5*H + 4*q);
            a += f6 * *(const v4f*)(W1 + 6*H + 4*q);
            a += f7 * *(const v4f*)(W1 + 7*H + 4*q);
            m1 += a[0] + a[1] + a[2] + a[3];
            q1 = fmaf(a[0], a[0], q1);
            q1 = fmaf(a[1], a[1], q1);
            q1 = fmaf(a[2], a[2], q1);
            q1 = fmaf(a[3], a[3], q1);
            hbuf[L*16 + (q ^ (L & 7))] = a;      // swizzled raw h
        }
        const float mu1  = m1 * (1.0f / H);
        const float var1 = fmaf(-mu1, mu1, q1 * (1.0f / H));
        const float rs1  = rsqrtf(var1 + EPS);
        scbuf[L] = make_float2(rs1, -mu1 * rs1);

        __syncthreads();                         // fence LDS cross-lane handoff (1 wave: cheap)

        // ---- Phase B: 4 M-tiles of 16 edges ----
        M_TILE(0); M_TILE(1); M_TILE(2); M_TILE(3);

        __syncthreads();                         // protect hbuf before next iteration's writes
    }
}

extern "C" void kernel_launch(void* const* d_in, const int* in_sizes, int n_in,
                              void* d_out, int out_size, void* d_ws, size_t ws_size,
                              hipStream_t stream) {
    const float* pos = (const float*)d_in[0];
    const float* vel = (const float*)d_in[1];
    const int*  eidx = (const int*)d_in[2];
    const float* W1  = (const float*)d_in[3];
    const float* b1  = (const float*)d_in[4];
    const float* g1  = (const float*)d_in[5];
    const float* be1 = (const float*)d_in[6];
    const float* W2  = (const float*)d_in[7];
    const float* b2  = (const float*)d_in[8];
    const float* g2  = (const float*)d_in[9];
    const float* be2 = (const float*)d_in[10];
    float* out = (float*)d_out;

    const int E = in_sizes[2] / 2;
    const int grid = (E + 64 * GPB - 1) / (64 * GPB);
    edge_mlp_mfma<<<grid, 64, 0, stream>>>(pos, vel, eidx, W1, b1, g1, be1,
                                           W2, b2, g2, be2, out, E);
}